// Round 17
// baseline (24019.081 us; speedup 1.0000x reference)
//
#include <hip/hip_runtime.h>
#include <hip/hip_fp16.h>

typedef _Float16 h2v __attribute__((ext_vector_type(2)));

__device__ __forceinline__ float fdot2(unsigned int a, unsigned int b, float c) {
    return __builtin_amdgcn_fdot2(__builtin_bit_cast(h2v, a),
                                  __builtin_bit_cast(h2v, b), c, false);
}

#define SCOPE_SYS __HIP_MEMORY_SCOPE_SYSTEM

// ---------------- fp32 -> fp16 convert (vectorized x4) ----------------
__global__ __launch_bounds__(256) void k_f2h(const float* __restrict__ src,
                                             __half* __restrict__ dst, int n4) {
    int i = blockIdx.x * 256 + threadIdx.x;
    if (i >= n4) return;
    float4 v = ((const float4*)src)[i];
    union { __half2 h[2]; uint2 u; } o;
    o.h[0] = __halves2half2(__float2half_rn(v.x), __float2half_rn(v.y));
    o.h[1] = __halves2half2(__float2half_rn(v.z), __float2half_rn(v.w));
    ((uint2*)dst)[i] = o.u;
}

__global__ __launch_bounds__(256) void k_bias(const float* __restrict__ a,
                                              const float* __restrict__ b,
                                              float* __restrict__ o) {
    int i = blockIdx.x * 256 + threadIdx.x;
    if (i < 4096) o[i] = a[i] + b[i];
}

// ---------------- x_gates GEMM: C[8192][4096] = A[8192][1024] @ B[4096][1024]^T + bias ----
__global__ __launch_bounds__(256) void k_gemm_xg(const __half* __restrict__ A,
                                                 const __half* __restrict__ B,
                                                 const float* __restrict__ bias,
                                                 __half* __restrict__ C) {
    __shared__ unsigned int As[128][20];
    __shared__ unsigned int Bs[128][20];
    const int tid = threadIdx.x;
    const int tx = tid & 15, ty = tid >> 4;
    const int m0 = blockIdx.x * 128, n0 = blockIdx.y * 128;
    float acc[8][8];
#pragma unroll
    for (int i = 0; i < 8; ++i)
#pragma unroll
        for (int j = 0; j < 8; ++j) acc[i][j] = 0.f;
    const unsigned int* Ag = (const unsigned int*)(A + (size_t)m0 * 1024);
    const unsigned int* Bg = (const unsigned int*)(B + (size_t)n0 * 1024);
    for (int k0 = 0; k0 < 512; k0 += 16) {
        __syncthreads();
#pragma unroll
        for (int j = 0; j < 2; ++j) {
            int qd = j * 256 + tid;
            int row = qd >> 2;
            int c4 = (qd & 3) << 2;
            uint4 va = *(const uint4*)(Ag + (size_t)row * 512 + k0 + c4);
            uint4 vb = *(const uint4*)(Bg + (size_t)row * 512 + k0 + c4);
            *(uint4*)&As[row][c4] = va;
            *(uint4*)&Bs[row][c4] = vb;
        }
        __syncthreads();
#pragma unroll
        for (int k2 = 0; k2 < 16; k2 += 2) {
            unsigned int a0[8], a1[8], b0[8], b1[8];
#pragma unroll
            for (int i = 0; i < 8; ++i) {
                uint2 v = *(const uint2*)&As[ty + 16 * i][k2];
                a0[i] = v.x; a1[i] = v.y;
            }
#pragma unroll
            for (int j = 0; j < 8; ++j) {
                uint2 v = *(const uint2*)&Bs[tx + 16 * j][k2];
                b0[j] = v.x; b1[j] = v.y;
            }
#pragma unroll
            for (int i = 0; i < 8; ++i)
#pragma unroll
                for (int j = 0; j < 8; ++j) {
                    acc[i][j] = fdot2(a0[i], b0[j], acc[i][j]);
                    acc[i][j] = fdot2(a1[i], b1[j], acc[i][j]);
                }
        }
    }
#pragma unroll
    for (int i = 0; i < 8; ++i) {
        int row = m0 + ty + 16 * i;
#pragma unroll
        for (int j = 0; j < 8; ++j) {
            int col = n0 + tx + 16 * j;
            C[(size_t)row * 4096 + col] = __float2half_rn(acc[i][j] + bias[col]);
        }
    }
}

// ---------------- persistent LSTM recurrence ----------------
// 64 blocks x 512 threads (8 waves). Block b owns 16 units [16b,16b+16);
// wave w owns units {16b+2w, 16b+2w+1} = 8 gate rows. Lane (rho=lane>>3,
// cc=lane&7): row rho (gate=rho&3, unit-local=rho>>2), k-chunk cc (128 halfs)
// -> 16 uint4 weight segments per lane.
// FULL LDS WEIGHT RESIDENCY (r17): all 128KB of this block's W_hh rows live
// in Wp[16][512] (loaded once). Zero per-step weight traffic -- no L2 stream,
// no scratch spill (VGPR stuck at 88 across r6/r7/r8/r15 attempts; r16's AGPR
// stash serialized). Per-lane dot work halves vs r12 (64 fdot2). The extra 32
// publishers/pollers cost ~+0.2us (measured herd slope) vs ~-0.33us compute.
// Handshake (r5/r12, best measured): system-scope relaxed 4B tagged stores
// {tag16|h16} one per unit; each poller lane reads ONE 8B word = two tagged
// halfs = its staged h2 dword. Tight spin, one barrier per step.
__global__ __launch_bounds__(512, 1) void k_lstm(const __half* __restrict__ Whh,
                                                 const __half* __restrict__ xg,
                                                 unsigned int* pub) { // [2][1024]
    __shared__ uint4 Wp[16][512];          // 128KB: ALL weight segs, resident
    __shared__ unsigned int hs[2][544];    // 8 groups of 64 dwords, stride 68
    const int tid = threadIdx.x;
    const int b = blockIdx.x;              // 0..63
    const int w = tid >> 6, lane = tid & 63;
    const int rho = lane >> 3;             // 0..7: gate=rho&3, unit-local=rho>>2
    const int cc = lane & 7;               // k-chunk (128 halfs)
    const int grow = (rho & 3) * 1024 + b * 16 + 2 * w + (rho >> 2);
    const unsigned int* gw = (const unsigned int*)(Whh + (size_t)grow * 1024 + cc * 128);
    // one-time: stage ALL 16 segments into LDS (segment i = 4 uints at gw+i*4)
#pragma unroll
    for (int i = 0; i < 16; ++i)
        Wp[i][tid] = *(const uint4*)(gw + i * 4);
    const int soff = (tid >> 6) * 68 + (tid & 63);   // hs slot for h2-dword tid
    const int upub = b * 16 + w * 2 + (lane >> 5);   // unit this lane may publish
    float c_state = 0.f;
    __syncthreads();

    for (int t = 0; t < 8192; ++t) {
        // x_gates prefetch (h-independent; overlaps the poll)
        float xv = __half2float(xg[(size_t)t * 4096 + grow]);
        unsigned int d = 0;
        if (t > 0) {
            const unsigned long long* src =
                (const unsigned long long*)(pub + (((t - 1) & 1) << 10)) + tid;
            const unsigned tt = (unsigned)t;
            unsigned long long v = __hip_atomic_load(src, __ATOMIC_RELAXED, SCOPE_SYS);
            unsigned lo = (unsigned)v, hi = (unsigned)(v >> 32);
            while ((lo >> 16) != tt || (hi >> 16) != tt) {
                v = __hip_atomic_load(src, __ATOMIC_RELAXED, SCOPE_SYS);
                lo = (unsigned)v; hi = (unsigned)(v >> 32);
            }
            d = (lo & 0xffffu) | (hi << 16);
        }
        const int p = t & 1;
        hs[p][soff] = d;
        __syncthreads();                   // the ONLY barrier per step
        float a0 = 0.f, a1 = 0.f, a2 = 0.f, a3 = 0.f;
        const unsigned int* hsp = &hs[p][cc * 68];   // this lane's 64-dword chunk
#pragma unroll
        for (int i = 0; i < 16; i += 4) {
            uint4 w0 = Wp[i + 0][tid];
            uint4 w1 = Wp[i + 1][tid];
            uint4 w2 = Wp[i + 2][tid];
            uint4 w3 = Wp[i + 3][tid];
            uint4 h0 = *(const uint4*)(hsp + (i + 0) * 4);
            uint4 h1 = *(const uint4*)(hsp + (i + 1) * 4);
            uint4 h2 = *(const uint4*)(hsp + (i + 2) * 4);
            uint4 h3 = *(const uint4*)(hsp + (i + 3) * 4);
            a0 = fdot2(w0.x, h0.x, a0); a1 = fdot2(w0.y, h0.y, a1);
            a2 = fdot2(w0.z, h0.z, a2); a3 = fdot2(w0.w, h0.w, a3);
            a0 = fdot2(w1.x, h1.x, a0); a1 = fdot2(w1.y, h1.y, a1);
            a2 = fdot2(w1.z, h1.z, a2); a3 = fdot2(w1.w, h1.w, a3);
            a0 = fdot2(w2.x, h2.x, a0); a1 = fdot2(w2.y, h2.y, a1);
            a2 = fdot2(w2.z, h2.z, a2); a3 = fdot2(w2.w, h2.w, a3);
            a0 = fdot2(w3.x, h3.x, a0); a1 = fdot2(w3.y, h3.y, a1);
            a2 = fdot2(w3.z, h3.z, a2); a3 = fdot2(w3.w, h3.w, a3);
        }
        float acc = (a0 + a1) + (a2 + a3);
        // reduce over the 8 k-chunks (lane bits 0..2)
        acc += __shfl_xor(acc, 1);
        acc += __shfl_xor(acc, 2);
        acc += __shfl_xor(acc, 4);
        acc += xv;
        // gather the 4 gates of unit (lane>>5): row rho=4u+g at lane 32u+8g
        const int base = lane & 32;
        float gi = __shfl(acc, base + 0);
        float gf = __shfl(acc, base + 8);
        float gg = __shfl(acc, base + 16);
        float go = __shfl(acc, base + 24);
        gi = 1.f / (1.f + __expf(-gi));
        gf = 1.f / (1.f + __expf(-gf));
        gg = 2.f / (1.f + __expf(-2.f * gg)) - 1.f;
        go = 1.f / (1.f + __expf(-go));
        c_state = gf * c_state + gi * gg;          // replicated per 32-lane group
        float hval = go * (2.f / (1.f + __expf(-2.f * c_state)) - 1.f);
        // publish: lanes 0 and 32 store their unit's tagged h
        if ((lane & 31) == 0) {
            unsigned val = ((unsigned)(t + 1) << 16) |
                           (unsigned)__half_as_ushort(__float2half_rn(hval));
            __hip_atomic_store(pub + (p << 10) + upub, val,
                               __ATOMIC_RELAXED, SCOPE_SYS);
        }
    }
}

// ---------------- final projection: out = h_final @ W_out^T + b_out ----------------
__global__ __launch_bounds__(256) void k_proj(const unsigned int* __restrict__ hfin,
                                              const float* __restrict__ Wout,
                                              const float* __restrict__ bout,
                                              float* __restrict__ out) {
    __shared__ float red[256];
    const int o = blockIdx.x, tid = threadIdx.x;
    const float* wr = Wout + (size_t)o * 1024;
    float acc = 0.f;
#pragma unroll
    for (int j = 0; j < 4; ++j) {
        int e = j * 256 + tid;
        unsigned v = hfin[e];              // {tag16 | h16}
        acc += __half2float(__ushort_as_half((unsigned short)(v & 0xffffu))) * wr[e];
    }
    red[tid] = acc;
    __syncthreads();
    for (int s = 128; s > 0; s >>= 1) {
        if (tid < s) red[tid] += red[tid + s];
        __syncthreads();
    }
    if (tid == 0) out[o] = red[0] + bout[o];
}

extern "C" void kernel_launch(void* const* d_in, const int* in_sizes, int n_in,
                              void* d_out, int out_size, void* d_ws, size_t ws_size,
                              hipStream_t stream) {
    const float* input_seq = (const float*)d_in[0];
    const float* W_ih = (const float*)d_in[1];
    const float* W_hh = (const float*)d_in[2];
    const float* b_ih = (const float*)d_in[3];
    const float* b_hh = (const float*)d_in[4];
    const float* W_out = (const float*)d_in[5];
    const float* b_out = (const float*)d_in[6];
    float* out = (float*)d_out;

    char* ws = (char*)d_ws;
    unsigned int* pub = (unsigned int*)ws;                         // [0, 8KB): [2][1024] tagged h
    float* bias = (float*)(ws + 24576);                            // [24KB, 40KB)
    __half* Wih_h = (__half*)(ws + 65536);                         // 8MB
    __half* Whh_h = (__half*)(ws + 65536 + (size_t)8 * 1024 * 1024);   // 8MB
    __half* in_h  = (__half*)(ws + 65536 + (size_t)16 * 1024 * 1024);  // 16MB
    __half* xg    = (__half*)(ws + 65536 + (size_t)32 * 1024 * 1024);  // 64MB

    // clear tags each call (graph replay determinism)
    hipMemsetAsync(ws, 0, 8192, stream);

    k_f2h<<<8192, 256, 0, stream>>>(input_seq, in_h, 2 * 1024 * 1024);
    k_f2h<<<4096, 256, 0, stream>>>(W_ih, Wih_h, 1024 * 1024);
    k_f2h<<<4096, 256, 0, stream>>>(W_hh, Whh_h, 1024 * 1024);
    k_bias<<<16, 256, 0, stream>>>(b_ih, b_hh, bias);

    dim3 gg(64, 32);
    k_gemm_xg<<<gg, 256, 0, stream>>>(in_h, Wih_h, bias, xg);

    k_lstm<<<64, 512, 0, stream>>>(Whh_h, xg, pub);

    k_proj<<<1024, 256, 0, stream>>>(pub + 1024, W_out, b_out, out);
}

// Round 18
// 17361.685 us; speedup vs baseline: 1.3835x; 1.3835x over previous
//
#include <hip/hip_runtime.h>
#include <hip/hip_fp16.h>

typedef _Float16 h2v __attribute__((ext_vector_type(2)));

__device__ __forceinline__ float fdot2(unsigned int a, unsigned int b, float c) {
    return __builtin_amdgcn_fdot2(__builtin_bit_cast(h2v, a),
                                  __builtin_bit_cast(h2v, b), c, false);
}

#define SCOPE_SYS __HIP_MEMORY_SCOPE_SYSTEM

// ---------------- fp32 -> fp16 convert (vectorized x4) ----------------
__global__ __launch_bounds__(256) void k_f2h(const float* __restrict__ src,
                                             __half* __restrict__ dst, int n4) {
    int i = blockIdx.x * 256 + threadIdx.x;
    if (i >= n4) return;
    float4 v = ((const float4*)src)[i];
    union { __half2 h[2]; uint2 u; } o;
    o.h[0] = __halves2half2(__float2half_rn(v.x), __float2half_rn(v.y));
    o.h[1] = __halves2half2(__float2half_rn(v.z), __float2half_rn(v.w));
    ((uint2*)dst)[i] = o.u;
}

__global__ __launch_bounds__(256) void k_bias(const float* __restrict__ a,
                                              const float* __restrict__ b,
                                              float* __restrict__ o) {
    int i = blockIdx.x * 256 + threadIdx.x;
    if (i < 4096) o[i] = a[i] + b[i];
}

// ---------------- x_gates GEMM: C[8192][4096] = A[8192][1024] @ B[4096][1024]^T + bias ----
__global__ __launch_bounds__(256) void k_gemm_xg(const __half* __restrict__ A,
                                                 const __half* __restrict__ B,
                                                 const float* __restrict__ bias,
                                                 __half* __restrict__ C) {
    __shared__ unsigned int As[128][20];
    __shared__ unsigned int Bs[128][20];
    const int tid = threadIdx.x;
    const int tx = tid & 15, ty = tid >> 4;
    const int m0 = blockIdx.x * 128, n0 = blockIdx.y * 128;
    float acc[8][8];
#pragma unroll
    for (int i = 0; i < 8; ++i)
#pragma unroll
        for (int j = 0; j < 8; ++j) acc[i][j] = 0.f;
    const unsigned int* Ag = (const unsigned int*)(A + (size_t)m0 * 1024);
    const unsigned int* Bg = (const unsigned int*)(B + (size_t)n0 * 1024);
    for (int k0 = 0; k0 < 512; k0 += 16) {
        __syncthreads();
#pragma unroll
        for (int j = 0; j < 2; ++j) {
            int qd = j * 256 + tid;
            int row = qd >> 2;
            int c4 = (qd & 3) << 2;
            uint4 va = *(const uint4*)(Ag + (size_t)row * 512 + k0 + c4);
            uint4 vb = *(const uint4*)(Bg + (size_t)row * 512 + k0 + c4);
            *(uint4*)&As[row][c4] = va;
            *(uint4*)&Bs[row][c4] = vb;
        }
        __syncthreads();
#pragma unroll
        for (int k2 = 0; k2 < 16; k2 += 2) {
            unsigned int a0[8], a1[8], b0[8], b1[8];
#pragma unroll
            for (int i = 0; i < 8; ++i) {
                uint2 v = *(const uint2*)&As[ty + 16 * i][k2];
                a0[i] = v.x; a1[i] = v.y;
            }
#pragma unroll
            for (int j = 0; j < 8; ++j) {
                uint2 v = *(const uint2*)&Bs[tx + 16 * j][k2];
                b0[j] = v.x; b1[j] = v.y;
            }
#pragma unroll
            for (int i = 0; i < 8; ++i)
#pragma unroll
                for (int j = 0; j < 8; ++j) {
                    acc[i][j] = fdot2(a0[i], b0[j], acc[i][j]);
                    acc[i][j] = fdot2(a1[i], b1[j], acc[i][j]);
                }
        }
    }
#pragma unroll
    for (int i = 0; i < 8; ++i) {
        int row = m0 + ty + 16 * i;
#pragma unroll
        for (int j = 0; j < 8; ++j) {
            int col = n0 + tx + 16 * j;
            C[(size_t)row * 4096 + col] = __float2half_rn(acc[i][j] + bias[col]);
        }
    }
}

// ---------------- persistent LSTM recurrence ----------------
// 32 blocks x 512 threads (8 waves). Block b owns hidden units [32b,32b+32);
// wave w owns units 32b+4w..+4 (4 units x 4 gates = 16 rows).
// Lane (rho=lane>>2, cc=lane&3): row rho (gate=rho&3, unit=rho>>2), k-chunk cc
// of 256 halfs = 32 uint4 weight segments per lane.
// Weights (r15, best): segs 0..17 persistent in LDS (144KB); segs 18..31 in
// pv[] with keep-alive pin (allocator spills them; reloads overlap the wait).
// WIDE POLL (r18): waves 0-3 (256 lanes) each poll ONE 16B dwordx4 (sc0 sc1)
// = 4 tagged words = 4 units -- covers all 1024 units in 256 transactions
// (r15: 512x8B). Each 4B word self-validates by tag, so tearing across the
// 16B load is harmless (r11 proved correctness). Each load covers exactly one
// publishing wave's 4 stores. Waves 4-7 skip polling, wait at the barrier.
// r17 measured the MALL transaction-count slope (2x transactions = +0.84us):
// this halves it without touching compute.
// Publish: system-scope relaxed 4B tagged stores {tag16|h16}, one per unit.
__global__ __launch_bounds__(512, 1) void k_lstm(const __half* __restrict__ Whh,
                                                 const __half* __restrict__ xg,
                                                 unsigned int* pub) { // [2][1024]
    __shared__ uint4 Wp[18][512];          // 144KB persistent weight segs 0..17
    __shared__ unsigned int hs[2][544];    // 8 groups of 64 dwords, stride 68
    const int tid = threadIdx.x;
    const int b = blockIdx.x;              // 0..31
    const int w = tid >> 6, lane = tid & 63;
    const int rho = lane >> 2;             // 0..15: gate=rho&3, unit-local=rho>>2
    const int cc = lane & 3;               // k-chunk (256 halfs)
    const int grow = (rho & 3) * 1024 + b * 32 + 4 * w + (rho >> 2);
    const unsigned int* gw = (const unsigned int*)(Whh + (size_t)grow * 1024 + cc * 256);
    // one-time: stage segments 0..17 into LDS (segment i = 4 uints at gw+i*4)
#pragma unroll
    for (int i = 0; i < 18; ++i)
        Wp[i][tid] = *(const uint4*)(gw + i * 4);
    // one-time: load streamed segments 18..31 into registers (pin below)
    uint4 pv[14];
#pragma unroll
    for (int i = 0; i < 14; ++i)
        pv[i] = *(const uint4*)(gw + (18 + i) * 4);
    const int soff = (tid >> 6) * 68 + (tid & 63);   // hs slot for h2-dword tid
    const int upub = b * 32 + w * 4 + (lane >> 4);   // unit this lane may publish
    // polling lanes (tid<256): stage h2-dwords e=2*tid, 2*tid+1 (even pair,
    // same 64-group -> one 8B write, 8B-aligned since group stride 68*4=272B)
    unsigned int* hst0 = &hs[0][((tid * 2) >> 6) * 68 + ((tid * 2) & 63)];
    unsigned int* hst1 = &hs[1][((tid * 2) >> 6) * 68 + ((tid * 2) & 63)];
    float c_state = 0.f;
    __syncthreads();

    for (int t = 0; t < 8192; ++t) {
        // keep-alive pin for pv (any spill reloads overlap the wait)
#pragma unroll
        for (int i = 0; i < 14; ++i)
            asm volatile("" : "+v"(pv[i].x), "+v"(pv[i].y), "+v"(pv[i].z), "+v"(pv[i].w));
        // x_gates prefetch (h-independent; overlaps the poll)
        float xv = __half2float(xg[(size_t)t * 4096 + grow]);
        const int p = t & 1;
        if (t > 0) {
            if (tid < 256) {
                const unsigned int* src = pub + (((t - 1) & 1) << 10) + (tid << 2);
                const unsigned tt = (unsigned)t;
                uint4 v;
                for (;;) {
                    asm volatile("global_load_dwordx4 %0, %1, off sc0 sc1\n\t"
                                 "s_waitcnt vmcnt(0)"
                                 : "=v"(v) : "v"(src) : "memory");
                    if ((v.x >> 16) == tt && (v.y >> 16) == tt &&
                        (v.z >> 16) == tt && (v.w >> 16) == tt) break;
                }
                unsigned d0 = (v.x & 0xffffu) | (v.y << 16);
                unsigned d1 = (v.z & 0xffffu) | (v.w << 16);
                unsigned int* dst = p ? hst1 : hst0;
                dst[0] = d0;
                dst[1] = d1;
            }
        } else {
            hs[p][soff] = 0u;              // all 512 lanes: full zero coverage
        }
        __syncthreads();                   // the ONLY barrier per step
        float a0 = 0.f, a1 = 0.f, a2 = 0.f, a3 = 0.f;
        const unsigned int* hsp = &hs[p][cc * 136];
        // LDS-resident segments (fast LDS pipe, conflict-free dense reads)
#pragma unroll
        for (int i = 0; i < 18; ++i) {
            uint4 wv = Wp[i][tid];
            uint4 h4 = *(const uint4*)(hsp + (i >> 4) * 68 + ((i & 15) << 2));
            a0 = fdot2(wv.x, h4.x, a0);
            a1 = fdot2(wv.y, h4.y, a1);
            a2 = fdot2(wv.z, h4.z, a2);
            a3 = fdot2(wv.w, h4.w, a3);
        }
        // register/spill segments
#pragma unroll
        for (int i = 0; i < 14; ++i) {
            int s = 18 + i;
            uint4 h4 = *(const uint4*)(hsp + (s >> 4) * 68 + ((s & 15) << 2));
            a0 = fdot2(pv[i].x, h4.x, a0);
            a1 = fdot2(pv[i].y, h4.y, a1);
            a2 = fdot2(pv[i].z, h4.z, a2);
            a3 = fdot2(pv[i].w, h4.w, a3);
        }
        float acc = (a0 + a1) + (a2 + a3);
        // reduce over the 4 k-chunks (lane bits 0..1)
        acc += __shfl_xor(acc, 1);
        acc += __shfl_xor(acc, 2);
        acc += xv;
        // gather the 4 gates of unit u = lane>>4 (row rho=4u+g at lane 16u+4g)
        const int base = lane & 48;
        float gi = __shfl(acc, base + 0);
        float gf = __shfl(acc, base + 4);
        float gg = __shfl(acc, base + 8);
        float go = __shfl(acc, base + 12);
        gi = 1.f / (1.f + __expf(-gi));
        gf = 1.f / (1.f + __expf(-gf));
        gg = 2.f / (1.f + __expf(-2.f * gg)) - 1.f;
        go = 1.f / (1.f + __expf(-go));
        c_state = gf * c_state + gi * gg;
        float hval = go * (2.f / (1.f + __expf(-2.f * c_state)) - 1.f);
        // publish: every 16-lane unit-group's lane 0 stores its unit's h
        if ((lane & 15) == 0) {
            unsigned val = ((unsigned)(t + 1) << 16) |
                           (unsigned)__half_as_ushort(__float2half_rn(hval));
            __hip_atomic_store(pub + (p << 10) + upub, val,
                               __ATOMIC_RELAXED, SCOPE_SYS);
        }
    }
}

// ---------------- final projection: out = h_final @ W_out^T + b_out ----------------
__global__ __launch_bounds__(256) void k_proj(const unsigned int* __restrict__ hfin,
                                              const float* __restrict__ Wout,
                                              const float* __restrict__ bout,
                                              float* __restrict__ out) {
    __shared__ float red[256];
    const int o = blockIdx.x, tid = threadIdx.x;
    const float* wr = Wout + (size_t)o * 1024;
    float acc = 0.f;
#pragma unroll
    for (int j = 0; j < 4; ++j) {
        int e = j * 256 + tid;
        unsigned v = hfin[e];              // {tag16 | h16}
        acc += __half2float(__ushort_as_half((unsigned short)(v & 0xffffu))) * wr[e];
    }
    red[tid] = acc;
    __syncthreads();
    for (int s = 128; s > 0; s >>= 1) {
        if (tid < s) red[tid] += red[tid + s];
        __syncthreads();
    }
    if (tid == 0) out[o] = red[0] + bout[o];
}

extern "C" void kernel_launch(void* const* d_in, const int* in_sizes, int n_in,
                              void* d_out, int out_size, void* d_ws, size_t ws_size,
                              hipStream_t stream) {
    const float* input_seq = (const float*)d_in[0];
    const float* W_ih = (const float*)d_in[1];
    const float* W_hh = (const float*)d_in[2];
    const float* b_ih = (const float*)d_in[3];
    const float* b_hh = (const float*)d_in[4];
    const float* W_out = (const float*)d_in[5];
    const float* b_out = (const float*)d_in[6];
    float* out = (float*)d_out;

    char* ws = (char*)d_ws;
    unsigned int* pub = (unsigned int*)ws;                         // [0, 8KB): [2][1024] tagged h
    float* bias = (float*)(ws + 24576);                            // [24KB, 40KB)
    __half* Wih_h = (__half*)(ws + 65536);                         // 8MB
    __half* Whh_h = (__half*)(ws + 65536 + (size_t)8 * 1024 * 1024);   // 8MB
    __half* in_h  = (__half*)(ws + 65536 + (size_t)16 * 1024 * 1024);  // 16MB
    __half* xg    = (__half*)(ws + 65536 + (size_t)32 * 1024 * 1024);  // 64MB

    // clear tags each call (graph replay determinism)
    hipMemsetAsync(ws, 0, 8192, stream);

    k_f2h<<<8192, 256, 0, stream>>>(input_seq, in_h, 2 * 1024 * 1024);
    k_f2h<<<4096, 256, 0, stream>>>(W_ih, Wih_h, 1024 * 1024);
    k_f2h<<<4096, 256, 0, stream>>>(W_hh, Whh_h, 1024 * 1024);
    k_bias<<<16, 256, 0, stream>>>(b_ih, b_hh, bias);

    dim3 gg(64, 32);
    k_gemm_xg<<<gg, 256, 0, stream>>>(in_h, Wih_h, bias, xg);

    k_lstm<<<32, 512, 0, stream>>>(Whh_h, xg, pub);

    k_proj<<<1024, 256, 0, stream>>>(pub + 1024, W_out, b_out, out);
}